// Round 4
// baseline (113.215 us; speedup 1.0000x reference)
//
#include <hip/hip_runtime.h>
#include <math.h>

#define Bn 8
#define Qn 20
#define Pn 12
#define Nn 4096
#define Gn 2048
#define Mn 1280   /* Q*FACTOR */
#define Fn 64
#define KNB 7     /* K_NEIGHBORS - 1 */
#define SA 8      /* gt splits for chamfer A (2048/256)  */
#define SB 5      /* recon splits for chamfer B (1280/256) */
#define NPROD 840 /* producer blocks: 160 cost + 40 rep + 640 chamfer */
#define NFIN 113  /* finale roles: 8 hungarian + 104 chamfer reduce + 1 rep reduce */
#define SCOPE_AGENT __HIP_MEMORY_SCOPE_AGENT

// ---------------- workspace layout (32-bit words) ----------------
// cham  : 0      (1920)   (B,Q,P)
// ns    : 1920   (1920)
// dd    : 3840   (1920)
// cost  : 5760   (1920)
// cnt   : 7680   (96)
// acc   : 7776   (6)      0 cls, 1 param, 2 pvd, 3 rep, 4 ch1, 5 ch2
// done  : 7782   (1)      producer counter   (poison-baseline relative)
// base  : 7783   (1)      NEVER WRITTEN -> holds the fill poison pattern
// c2    : 7784   (1)      finale counter     (poison-baseline relative)
// rep   : 7808   (160)    per-group repulsion partials
// pmA1  : 8192   (81920)  chamfer A partial mins (SA, B*M)
// pmA2  : 90112  (81920)
// pmB1  : 172032 (81920)  (SB, B*G)
// pmB2  : 253952 (81920)  .. 335872
//
// R10: SINGLE-DISPATCH fusion. Accounting across R0/R7/R8/R9 fits
// total = 40(fill) + work + ~20us * n_dispatches  -- the kernels were never
// 39/30us; the boundaries were. Fusing mega1+finale removes one boundary.
// Coherence WITHOUT the R5/R6 per-block-threadfence cost (~20us of refetch):
// all cross-block data moves via agent-scope atomic stores/loads (sc-bit ops
// that bypass the non-coherent per-XCD L2), producers end with a release-RMW
// on `done`, finale roles acquire-spin until done-init==840. Counters are
// poison-baseline-relative (ws is re-poisoned each iteration; `base` gives
// the pattern) and restored by the assembler. Deadlock-free: 24.6KB LDS =>
// >=6 blocks/CU => all 840 blocks co-resident; spinners (<=113) can never
// starve producers.

__device__ __forceinline__ float aread(float* p) { return atomicAdd(p, 0.0f); }
__device__ __forceinline__ void ast(float* p, float v) {
    __hip_atomic_store(p, v, __ATOMIC_RELAXED, SCOPE_AGENT);
}
__device__ __forceinline__ float ald(const float* p) {
    return __hip_atomic_load(p, __ATOMIC_RELAXED, SCOPE_AGENT);
}

// --- cross-lane helpers ---
__device__ __forceinline__ int rdlane_i(int v, int l) {
    return __builtin_amdgcn_readlane(v, l);
}
__device__ __forceinline__ float rdlane_f(float v, int l) {
    return __int_as_float(__builtin_amdgcn_readlane(__float_as_int(v), l));
}
// full-wave min via DPP (VALU pipe, ~6 dependent ops); result valid in lane 63.
__device__ __forceinline__ unsigned wave_min_u32(unsigned x) {
    unsigned t;
    t = (unsigned)__builtin_amdgcn_update_dpp((int)0xFFFFFFFF, (int)x, 0x111, 0xF, 0xF, false);
    x = t < x ? t : x;   // row_shr:1
    t = (unsigned)__builtin_amdgcn_update_dpp((int)0xFFFFFFFF, (int)x, 0x112, 0xF, 0xF, false);
    x = t < x ? t : x;   // row_shr:2
    t = (unsigned)__builtin_amdgcn_update_dpp((int)0xFFFFFFFF, (int)x, 0x114, 0xF, 0xF, false);
    x = t < x ? t : x;   // row_shr:4
    t = (unsigned)__builtin_amdgcn_update_dpp((int)0xFFFFFFFF, (int)x, 0x118, 0xF, 0xF, false);
    x = t < x ? t : x;   // row_shr:8  -> lane 15/31/47/63 hold row mins
    t = (unsigned)__builtin_amdgcn_update_dpp((int)0xFFFFFFFF, (int)x, 0x142, 0xF, 0xF, false);
    x = t < x ? t : x;   // row_bcast:15 -> lane 31 = min(0..31), 63 = min(32..63)
    t = (unsigned)__builtin_amdgcn_update_dpp((int)0xFFFFFFFF, (int)x, 0x143, 0xF, 0xF, false);
    x = t < x ? t : x;   // row_bcast:31 -> lane 63 = min(all)
    return x;
}

// finale-role completion: last of NFIN assembles out, restores counters.
__device__ __forceinline__ void finpost(float* ws, float* out, unsigned init) {
    unsigned* doneP = (unsigned*)(ws + 7782);
    unsigned* c2P   = (unsigned*)(ws + 7784);
    float* acc = ws + 7776;
    unsigned old = __hip_atomic_fetch_add(c2P, 1u, __ATOMIC_ACQ_REL, SCOPE_AGENT);
    if (old - init == (unsigned)(NFIN - 1)) {
        float a0 = aread(&acc[0]);
        float a1 = aread(&acc[1]);
        float a2 = aread(&acc[2]);
        float a3 = aread(&acc[3]);
        float a4 = aread(&acc[4]);
        float a5 = aread(&acc[5]);
        out[0] = a0 + 0.5f * a1 + 20.f * a2 + a3 + a4 + a5;
        // restore so the scheme works even if an iteration skips re-poison
        __hip_atomic_store(doneP, init, __ATOMIC_RELAXED, SCOPE_AGENT);
        __hip_atomic_store(c2P,   init, __ATOMIC_RELAXED, SCOPE_AGENT);
    }
}

// ============ fused: producers (840 blocks) -> spin -> finale roles (113) ============
__global__ void fused_kernel(const float* __restrict__ pred_logits,
                             const float* __restrict__ pred_normals,
                             const float* __restrict__ pred_distances,
                             const float* __restrict__ gt_normals,
                             const float* __restrict__ gt_distances,
                             const float* __restrict__ points,
                             const int*   __restrict__ gt_masks,
                             const float* __restrict__ recon,
                             const float* __restrict__ gt,
                             float* __restrict__ ws,
                             float* __restrict__ out) {
    __shared__ __align__(16) float smem[2 * Pn * 256];
    const int blk = blockIdx.x;
    const int tid = threadIdx.x;

    float* cham = ws;
    float* ns   = ws + 1920;
    float* dd   = ws + 3840;
    float* cost = ws + 5760;
    float* cnt  = ws + 7680;
    float* acc  = ws + 7776;
    unsigned* doneP = (unsigned*)(ws + 7782);
    unsigned* baseP = (unsigned*)(ws + 7783);
    float* rep_part = ws + 7808;
    float* pmA1 = ws + 8192;
    float* pmA2 = ws + 90112;
    float* pmB1 = ws + 172032;
    float* pmB2 = ws + 253952;

    const unsigned init = __hip_atomic_load(baseP, __ATOMIC_RELAXED, SCOPE_AGENT);

    // ================= producer phase =================
    if (blk < 160) {
        // ---- cost path: one block per (b,q) ----
        if (blk == 0 && tid < 6) ast(&acc[tid], 0.f);   // zero BEFORE release-bump
        const int b = blk / Qn, q = blk % Qn;
        const float nx = pred_normals[(b * Qn + q) * 3 + 0];
        const float ny = pred_normals[(b * Qn + q) * 3 + 1];
        const float nz = pred_normals[(b * Qn + q) * 3 + 2];
        const float dq = pred_distances[b * Qn + q];

        float accs[Pn], accw[Pn];
#pragma unroll
        for (int p = 0; p < Pn; ++p) { accs[p] = 0.f; accw[p] = 0.f; }

        const float* ptb = points + (size_t)b * Nn * 3;
        const int*   mb  = gt_masks + (size_t)b * Pn * Nn;

        for (int n = tid; n < Nn; n += 256) {
            float px = ptb[n * 3 + 0], py = ptb[n * 3 + 1], pz = ptb[n * 3 + 2];
            float pp = fabsf(px * nx + py * ny + pz * nz - dq);
#pragma unroll
            for (int p = 0; p < Pn; ++p) {
                float m = (float)mb[(size_t)p * Nn + n];
                accs[p] += pp * m;
                accw[p] += m;
            }
        }
#pragma unroll
        for (int p = 0; p < Pn; ++p) {
            smem[p * 256 + tid] = accs[p];
            smem[(p + Pn) * 256 + tid] = accw[p];
        }
        __syncthreads();
        for (int off = 128; off > 0; off >>= 1) {
            if (tid < off) {
#pragma unroll
                for (int r = 0; r < 2 * Pn; ++r) smem[r * 256 + tid] += smem[r * 256 + tid + off];
            }
            __syncthreads();
        }
        if (tid < Pn) {
            const int p = tid;
            float c  = smem[(p + Pn) * 256];
            float cv = smem[p * 256] / fmaxf(c, 1.f);
            float gnx = gt_normals[(b * Pn + p) * 3 + 0];
            float gny = gt_normals[(b * Pn + p) * 3 + 1];
            float gnz = gt_normals[(b * Pn + p) * 3 + 2];
            float nsim = 1.f - fabsf(nx * gnx + ny * gny + nz * gnz);
            float ddv  = fabsf(dq - gt_distances[b * Pn + p]);
            int idx = (b * Qn + q) * Pn + p;
            ast(&cham[idx], cv);
            ast(&ns[idx],   nsim);
            ast(&dd[idx],   ddv);
            ast(&cost[idx], nsim + 0.5f * ddv + 5.f * ((c > 0.f) ? cv : 1.f));
            if (q == 0) ast(&cnt[b * Pn + p], c);
        }
    } else if (blk < 200) {
        // ---- repulsion: 4 waves per block, one (b,q) 64-pt group per wave ----
        const int wave = tid >> 6, lane = tid & 63;
        const int g = (blk - 160) * 4 + wave;
        float* xs = smem + wave * 192;
        float* ys = xs + 64;
        float* zs = xs + 128;
        const float* base = recon + (size_t)g * Fn * 3;
        xs[lane] = base[lane * 3 + 0];
        ys[lane] = base[lane * 3 + 1];
        zs[lane] = base[lane * 3 + 2];
        // wave-local LDS region: wave-synchronous access
        float best[KNB];
#pragma unroll
        for (int k = 0; k < KNB; ++k) best[k] = 3.4e38f;
        const float xi = xs[lane], yi = ys[lane], zi = zs[lane];
        for (int j = 0; j < Fn; ++j) {
            float dx = xi - xs[j], dy = yi - ys[j], dz = zi - zs[j];
            float d2 = dx * dx + dy * dy + dz * dz;
            d2 = (j == lane) ? 3.4e38f : d2;   // exclude self, keep lanes convergent
#pragma unroll
            for (int k = 0; k < KNB; ++k) {    // one bubble pass; best stays sorted asc
                float lo = fminf(best[k], d2);
                float hi = fmaxf(best[k], d2);
                best[k] = lo;
                d2 = hi;
            }
        }
        float sum = 0.f;
#pragma unroll
        for (int k = 0; k < KNB; ++k) {
            float dn = fmaxf(best[k], 1e-12f);
            float w  = expf(-dn / (0.03f * 0.03f));
            sum += (0.07f - sqrtf(dn)) * w;
        }
        for (int off = 32; off > 0; off >>= 1) sum += __shfl_down(sum, off);
        if (lane == 0) ast(&rep_part[g], fmaxf(sum / (float)(Fn * KNB), 0.f));
    } else {
        // ---- chamfer partial: float4 LDS tile (b128 broadcast reads) + unroll 4 ----
        int cblk = blk - 200;
        float4* tile = reinterpret_cast<float4*>(smem);
        float x, y, z;
        const float* inner;
        float *o1, *o2;
        int idx;
        if (cblk < 40 * SA) {
            int s = cblk % SA, ob = cblk / SA;
            idx = ob * 256 + tid;                 // over B*M
            int b = idx / Mn;
            x = recon[idx * 3 + 0]; y = recon[idx * 3 + 1]; z = recon[idx * 3 + 2];
            inner = gt + ((size_t)b * Gn + s * 256) * 3;
            o1 = pmA1 + s * (Bn * Mn); o2 = pmA2 + s * (Bn * Mn);
        } else {
            cblk -= 40 * SA;
            int s = cblk % SB, ob = cblk / SB;
            idx = ob * 256 + tid;                 // over B*G
            int b = idx / Gn;
            x = gt[idx * 3 + 0]; y = gt[idx * 3 + 1]; z = gt[idx * 3 + 2];
            inner = recon + ((size_t)b * Mn + s * 256) * 3;
            o1 = pmB1 + s * (Bn * Gn); o2 = pmB2 + s * (Bn * Gn);
        }
        {
            const float* ip = inner + tid * 3;
            float4 tv;
            tv.x = ip[0]; tv.y = ip[1]; tv.z = ip[2]; tv.w = 0.f;
            tile[tid] = tv;
        }
        __syncthreads();
        float m1 = 3.4e38f, m2 = 3.4e38f;
#pragma unroll 4
        for (int j = 0; j < 256; ++j) {
            float4 tv = tile[j];
            float dx = x - tv.x, dy = y - tv.y, dz = z - tv.z;
            float d1 = fabsf(dx) + fabsf(dy) + fabsf(dz);
            float d2 = dx * dx + dy * dy + dz * dz;
            m1 = fminf(m1, d1); m2 = fminf(m2, d2);
        }
        ast(&o1[idx], m1);
        ast(&o2[idx], m2);
    }

    // barrier drains every wave's outstanding stores (s_waitcnt vmcnt(0) before
    // s_barrier), then one release-RMW publishes the block's work.
    __syncthreads();
    if (tid == 0) __hip_atomic_fetch_add(doneP, 1u, __ATOMIC_RELEASE, SCOPE_AGENT);

    if (blk >= NFIN) return;

    // ================= spin until all producers published =================
    if (tid == 0) {
        while (__hip_atomic_load(doneP, __ATOMIC_RELAXED, SCOPE_AGENT) - init != (unsigned)NPROD)
            __builtin_amdgcn_s_sleep(2);
        (void)__hip_atomic_load(doneP, __ATOMIC_ACQUIRE, SCOPE_AGENT);
    }
    __syncthreads();

    // ================= finale phase =================
    if (blk < 8) {
        // ---- wave-parallel transposed rectangular JV, f32 + DPP argmin ----
        // Exactness: the optimal assignment is unique a.s.; f32 JV (err ~1e-6,
        // gaps ~1e-2) returns the same matching, hence a bitwise-identical loss.
        if (tid < 64) {
            const int b = blk;
            const int t = tid;
            const int col = t;
            const bool isCol = (col >= 1 && col <= Qn);

            float cr[Pn];
#pragma unroll
            for (int k = 0; k < Pn; ++k) cr[k] = 0.f;
            if (isCol) {
                const float* cb = cost + ((size_t)b * Qn + (col - 1)) * Pn;
#pragma unroll
                for (int k = 0; k < Pn; ++k) cr[k] = ald(&cb[k]);
            }

            float v = 0.f, u = 0.f, minv = 0.f;
            int way = 0, p = 0;

            for (int i = 1; i <= Pn; ++i) {
                minv = 1e30f;
                bool used = false;
                bool rowInPath = false;
                int j0s = 0;
                while (true) {
                    if (col == j0s) used = true;
                    int i0s = (j0s == 0) ? i : rdlane_i(p, j0s);
                    if (t == i0s) rowInPath = true;
                    float u_i0 = rdlane_f(u, i0s);
                    // depth-4 select of cr[i0s-1] (i0s wave-uniform, 1..12)
                    const int bs = i0s - 1;
                    float l10 = (bs & 1) ? cr[1]  : cr[0];
                    float l11 = (bs & 1) ? cr[3]  : cr[2];
                    float l12 = (bs & 1) ? cr[5]  : cr[4];
                    float l13 = (bs & 1) ? cr[7]  : cr[6];
                    float l14 = (bs & 1) ? cr[9]  : cr[8];
                    float l15 = (bs & 1) ? cr[11] : cr[10];
                    float l20 = (bs & 2) ? l11 : l10;
                    float l21 = (bs & 2) ? l13 : l12;
                    float l22 = (bs & 2) ? l15 : l14;
                    float cij = (bs >= 8) ? l22 : ((bs >= 4) ? l21 : l20);
                    if (isCol && !used) {
                        float cur = cij - u_i0 - v;
                        if (cur < minv) { minv = cur; way = j0s; }
                    }
                    float mv = (isCol && !used) ? minv : 1e30f;
                    // monotone u32 key, col in low 5 bits (col<=20<32); min => lowest
                    // col on equal key == reference's ascending strict-< scan.
                    unsigned kb = __float_as_uint(mv);
                    kb = ((int)kb < 0) ? ~kb : (kb | 0x80000000u);
                    kb = (kb & ~31u) | (unsigned)(col & 31);
                    unsigned kmin = (unsigned)rdlane_i((int)wave_min_u32(kb), 63);
                    int j1 = (int)(kmin & 31u);
                    float delta = rdlane_f(minv, j1);   // exact lane value, not key bits
                    if (used || col == 0) v -= delta;
                    else if (isCol)       minv -= delta;
                    if (rowInPath)        u += delta;
                    j0s = j1;
                    int pj0 = rdlane_i(p, j0s);
                    if (pj0 == 0) break;
                }
                while (j0s != 0) {
                    int wj = rdlane_i(way, j0s);
                    int pw = (wj == 0) ? i : rdlane_i(p, wj);
                    if (col == j0s) p = pw;
                    j0s = wj;
                }
            }

            float cls = 0.f, par = 0.f, pvd = 0.f;
            if (isCol) {
                float x = pred_logits[b * Qn + (col - 1)];
                float tgt = (p > 0) ? 1.f : 0.f;
                cls = fmaxf(x, 0.f) - x * tgt + log1pf(expf(-fabsf(x)));
                if (p > 0) {
                    int idx = (b * Qn + (col - 1)) * Pn + (p - 1);
                    par = ald(&ns[idx]) + ald(&dd[idx]);
                    pvd = (ald(&cnt[b * Pn + (p - 1)]) > 0.f) ? ald(&cham[idx]) : 0.f;
                }
            }
            for (int off = 32; off > 0; off >>= 1) {
                cls += __shfl_down(cls, off);
                par += __shfl_down(par, off);
                pvd += __shfl_down(pvd, off);
            }
            if (t == 0) {
                atomicAdd(&acc[0], cls / (float)(Bn * Qn));
                atomicAdd(&acc[1], par / (float)(Bn * Pn));
                atomicAdd(&acc[2], pvd / (float)(Bn * Pn));
                finpost(ws, out, init);
            }
        }
        return;
    }

    // ---- chamfer reduce (blocks 8..111) + repulsion reduce (block 112) ----
    {
        float* s1 = smem;
        float* s2 = smem + 256;
        const int cblk = blk - 8;
        float c1 = 0.f, c2 = 0.f;
        if (cblk < 40) {
            int idx = cblk * 256 + tid;
            float m1 = 3.4e38f, m2 = 3.4e38f;
#pragma unroll
            for (int s = 0; s < SA; ++s) {
                m1 = fminf(m1, ald(&pmA1[s * (Bn * Mn) + idx]));
                m2 = fminf(m2, ald(&pmA2[s * (Bn * Mn) + idx]));
            }
            c1 = m1 * (0.5f / (float)(Bn * Mn));
            c2 = m2 * (0.5f / (float)(Bn * Mn));
        } else if (cblk < 104) {
            int idx = (cblk - 40) * 256 + tid;
            float m1 = 3.4e38f, m2 = 3.4e38f;
#pragma unroll
            for (int s = 0; s < SB; ++s) {
                m1 = fminf(m1, ald(&pmB1[s * (Bn * Gn) + idx]));
                m2 = fminf(m2, ald(&pmB2[s * (Bn * Gn) + idx]));
            }
            c1 = m1 * (0.5f / (float)(Bn * Gn));
            c2 = m2 * (0.5f / (float)(Bn * Gn));
        } else {
            c1 = (tid < Bn * Qn) ? ald(&rep_part[tid]) / (float)(Bn * Qn) : 0.f;
        }
        s1[tid] = c1; s2[tid] = c2;
        __syncthreads();
        for (int off = 128; off > 0; off >>= 1) {
            if (tid < off) { s1[tid] += s1[tid + off]; s2[tid] += s2[tid + off]; }
            __syncthreads();
        }
        if (tid == 0) {
            if (cblk < 104) {
                atomicAdd(&acc[4], s1[0]);
                atomicAdd(&acc[5], s2[0]);
            } else {
                atomicAdd(&acc[3], s1[0]);
            }
            finpost(ws, out, init);
        }
    }
}

extern "C" void kernel_launch(void* const* d_in, const int* in_sizes, int n_in,
                              void* d_out, int out_size, void* d_ws, size_t ws_size,
                              hipStream_t stream) {
    const float* pred_logits    = (const float*)d_in[0];
    const float* pred_normals   = (const float*)d_in[1];
    const float* pred_distances = (const float*)d_in[2];
    const float* gt_normals     = (const float*)d_in[3];
    const float* gt_distances   = (const float*)d_in[4];
    const int*   gt_masks       = (const int*)d_in[5];
    const float* points         = (const float*)d_in[6];
    const float* recon          = (const float*)d_in[7];
    const float* gt             = (const float*)d_in[8];
    // d_in[9] (gt_index) is unused by the reference.

    fused_kernel<<<NPROD, 256, 0, stream>>>(pred_logits, pred_normals, pred_distances,
                                            gt_normals, gt_distances, points, gt_masks,
                                            recon, gt, (float*)d_ws, (float*)d_out);
}